// Round 1
// baseline (224.465 us; speedup 1.0000x reference)
//
#include <hip/hip_runtime.h>

// PermuteWeightSharing: out[row, s*16+k] = x[row, ppos[s]*16+k] - x[row, pneg[s]*16+k]
// row = (b,o,i) flattened, 256 floats per row = 16 slots x 16 floats.
// Ppos/Pneg are 16x16 one-hot permutation matrices; decode argmax per row once
// per block into LDS. Memory-bound shuffle: ~256 MiB HBM traffic, floor ~43 us.

#define NSLOTS 16
// 256 floats per row -> 64 float4 per row; slot = 4 float4 (one 64B block)

__global__ __launch_bounds__(256) void permute_ws_kernel(
    const float4* __restrict__ x,
    const float* __restrict__ Ppos,
    const float* __restrict__ Pneg,
    float4* __restrict__ out,
    long total_v4)
{
    __shared__ int spos[NSLOTS];
    __shared__ int sneg[NSLOTS];

    const int t = threadIdx.x;
    if (t < NSLOTS) {
        // decode one-hot row t of each permutation matrix
        int ip = 0, in_ = 0;
        #pragma unroll
        for (int j = 0; j < NSLOTS; ++j) {
            if (Ppos[t * NSLOTS + j] > 0.5f) ip = j;
            if (Pneg[t * NSLOTS + j] > 0.5f) in_ = j;
        }
        spos[t] = ip;
        sneg[t] = in_;
    }
    __syncthreads();

    long idx = (long)blockIdx.x * blockDim.x + threadIdx.x;
    const long stride = (long)gridDim.x * blockDim.x;

    for (; idx < total_v4; idx += stride) {
        const long row_base = idx & ~63L;   // start of this 256-float row (in float4 units)
        const int  v        = (int)(idx & 63);  // float4 index within row [0,64)
        const int  slot     = v >> 2;           // [0,16)
        const int  k4       = v & 3;            // [0,4)

        const float4 a = x[row_base + ((long)spos[slot] << 2) + k4];
        const float4 b = x[row_base + ((long)sneg[slot] << 2) + k4];

        float4 r;
        r.x = a.x - b.x;
        r.y = a.y - b.y;
        r.z = a.z - b.z;
        r.w = a.w - b.w;
        out[idx] = r;
    }
}

extern "C" void kernel_launch(void* const* d_in, const int* in_sizes, int n_in,
                              void* d_out, int out_size, void* d_ws, size_t ws_size,
                              hipStream_t stream)
{
    const float4* x    = (const float4*)d_in[0];
    const float*  Ppos = (const float*)d_in[1];
    const float*  Pneg = (const float*)d_in[2];
    float4*       out  = (float4*)d_out;

    const long total_v4 = (long)out_size / 4;   // 33,554,432 / 4 = 8,388,608

    const int block = 256;
    long blocks_needed = (total_v4 + block - 1) / block;  // 32768
    int grid = (int)(blocks_needed > 32768 ? 32768 : blocks_needed);

    permute_ws_kernel<<<grid, block, 0, stream>>>(x, Ppos, Pneg, out, total_v4);
}